// Round 9
// baseline (211.282 us; speedup 1.0000x reference)
//
#include <hip/hip_runtime.h>
#include <math.h>

#define B_DIM 4
#define S_DIM 4096
#define E_DIM 1024
#define A_DIM 64
#define M_TOT (B_DIM * S_DIM) /* 16384 */

typedef __bf16 v8bf __attribute__((ext_vector_type(8)));
typedef __bf16 v4bf __attribute__((ext_vector_type(4)));
typedef float  v4f  __attribute__((ext_vector_type(4)));

__device__ __forceinline__ v4f mfma16(v8bf a, v8bf b, v4f c) {
    return __builtin_amdgcn_mfma_f32_16x16x32_bf16(a, b, c, 0, 0, 0);
}

// ---------------------------------------------------------------------------
// Pre-pass: fp32 weights -> bf16 Wb[192][1024] (rows 0-63 K, 64-127 Q, 128-191 V).
// ---------------------------------------------------------------------------
__global__ __launch_bounds__(256) void wconv_kernel(
    const float* __restrict__ Wk, const float* __restrict__ Wq,
    const float* __restrict__ Wv, __bf16* __restrict__ Wb)
{
    const int i = blockIdx.x * 256 + threadIdx.x;   // float4 index, 49152 total
    const int w = i >> 14;
    const int off = (i & 16383) * 4;
    const float* s = ((w == 0) ? Wk : (w == 1) ? Wq : Wv) + off;
    float4 v = *(const float4*)s;
    v4bf o;
    o[0] = (__bf16)v.x; o[1] = (__bf16)v.y; o[2] = (__bf16)v.z; o[3] = (__bf16)v.w;
    *(v4bf*)(Wb + (size_t)w * 65536 + off) = o;
}

// ---------------------------------------------------------------------------
// Fused QKV projection v7: pure-TLP streaming split-K GEMM.
// grid = 1024 row-tiles x 2 k-slices = 2048 blocks x 4 waves -> 8 blocks/CU,
// 32 waves/CU (100% occupancy; launch_bounds(256,8) caps VGPR at 64).
// Wave w owns 48 cols; 16 kc iterations of {2 A-loads, 3 B-loads, 3 MFMA};
// NO LDS, NO barriers, fp32 partials out.  Latency hiding = 8 waves/SIMD.
// ---------------------------------------------------------------------------
__global__ __launch_bounds__(256, 8) void qkv_proj_mfma(
    const float* __restrict__ X,
    const __bf16* __restrict__ Wb,   // [192][1024]
    float* __restrict__ Pp)          // [2][16384][192] fp32 partials
{
    const int r0   = (blockIdx.x >> 1) * 16;
    const int ky   = blockIdx.x & 1;         // k-slice: kc chunks [16ky, 16ky+16)
    const int w    = threadIdx.x >> 6;
    const int lane = threadIdx.x & 63;
    const int L    = lane & 15;
    const int quad = lane >> 4;
    const int cbase = w * 48;

    v4f acc[3];
#pragma unroll
    for (int nt = 0; nt < 3; ++nt) acc[nt] = (v4f){0.f, 0.f, 0.f, 0.f};

    const int kq = quad * 8;
    const float*  Arow  = X + (size_t)(r0 + L) * E_DIM;
    const __bf16* Brow0 = Wb + (size_t)(cbase + 0 * 16 + L) * E_DIM;
    const __bf16* Brow1 = Wb + (size_t)(cbase + 1 * 16 + L) * E_DIM;
    const __bf16* Brow2 = Wb + (size_t)(cbase + 2 * 16 + L) * E_DIM;

#pragma unroll 1
    for (int kc = 0; kc < 16; ++kc) {
        const int k0 = (ky * 16 + kc) * 32 + kq;
        const float4 a0 = *(const float4*)(Arow + k0);
        const float4 a1 = *(const float4*)(Arow + k0 + 4);
        v8bf af;
        af[0] = (__bf16)a0.x; af[1] = (__bf16)a0.y;
        af[2] = (__bf16)a0.z; af[3] = (__bf16)a0.w;
        af[4] = (__bf16)a1.x; af[5] = (__bf16)a1.y;
        af[6] = (__bf16)a1.z; af[7] = (__bf16)a1.w;
        const v8bf b0 = *(const v8bf*)(Brow0 + k0);
        const v8bf b1 = *(const v8bf*)(Brow1 + k0);
        const v8bf b2 = *(const v8bf*)(Brow2 + k0);
        acc[0] = mfma16(af, b0, acc[0]);
        acc[1] = mfma16(af, b1, acc[1]);
        acc[2] = mfma16(af, b2, acc[2]);
    }

    // fp32 partials, written exactly once per element (no init needed)
    float* dst = Pp + ((size_t)ky * M_TOT + r0) * 192;
#pragma unroll
    for (int nt = 0; nt < 3; ++nt)
#pragma unroll
        for (int r = 0; r < 4; ++r)
            dst[(size_t)(quad * 4 + r) * 192 + cbase + nt * 16 + L] = acc[nt][r];
}

// ---------------------------------------------------------------------------
// Reduce the 2 k-slice partials and emit bf16 K, Q (x 1/8), V^T.
// grid = 256 blocks (64 rows each) x 256 thr.
// ---------------------------------------------------------------------------
__global__ __launch_bounds__(256) void qkv_reduce(
    const float* __restrict__ Pp,
    __bf16* __restrict__ Kb,
    __bf16* __restrict__ Qb,
    __bf16* __restrict__ Vt)
{
    const int r0 = blockIdx.x * 64;
    const int t  = threadIdx.x;
    __shared__ float Tv[64][65];

    const float* P0 = Pp + (size_t)r0 * 192;
    const float* P1 = Pp + (size_t)(M_TOT + r0) * 192;

    // ---- K / Q: thread -> row = t>>2, 32-col group = (t&3)*32 (cols 0..127)
    {
        const int row = t >> 2;
        const int cg  = (t & 3) * 32;
        const float* p0 = P0 + (size_t)row * 192 + cg;
        const float* p1 = P1 + (size_t)row * 192 + cg;
        const bool  isQ = (cg >= 64);
        const float sc  = isQ ? 0.125f : 1.0f;
        __bf16* dst = isQ ? (Qb + (size_t)(r0 + row) * A_DIM + (cg - 64))
                          : (Kb + (size_t)(r0 + row) * A_DIM + cg);
#pragma unroll
        for (int h = 0; h < 4; ++h) { // 4 groups of 8 cols
            float4 a0 = ((const float4*)p0)[h * 2 + 0];
            float4 a1 = ((const float4*)p0)[h * 2 + 1];
            float4 b0 = ((const float4*)p1)[h * 2 + 0];
            float4 b1 = ((const float4*)p1)[h * 2 + 1];
            v8bf o;
            o[0] = (__bf16)((a0.x + b0.x) * sc); o[1] = (__bf16)((a0.y + b0.y) * sc);
            o[2] = (__bf16)((a0.z + b0.z) * sc); o[3] = (__bf16)((a0.w + b0.w) * sc);
            o[4] = (__bf16)((a1.x + b1.x) * sc); o[5] = (__bf16)((a1.y + b1.y) * sc);
            o[6] = (__bf16)((a1.z + b1.z) * sc); o[7] = (__bf16)((a1.w + b1.w) * sc);
            *(v8bf*)(dst + h * 8) = o;
        }
    }

    // ---- V (cols 128..191): sum into LDS, then transposed write
    {
        const int row = t >> 2;
        const int cg  = (t & 3) * 16;
        const float* p0 = P0 + (size_t)row * 192 + 128 + cg;
        const float* p1 = P1 + (size_t)row * 192 + 128 + cg;
#pragma unroll
        for (int h = 0; h < 4; ++h) {
            float4 a = ((const float4*)p0)[h];
            float4 b = ((const float4*)p1)[h];
            Tv[row][cg + h * 4 + 0] = a.x + b.x;
            Tv[row][cg + h * 4 + 1] = a.y + b.y;
            Tv[row][cg + h * 4 + 2] = a.z + b.z;
            Tv[row][cg + h * 4 + 3] = a.w + b.w;
        }
    }
    __syncthreads();
    {
        const int a  = t & 63;
        const int sg = (t >> 6) * 16;
        const int batch = r0 >> 12;
        const int s0    = r0 & 4095;
        __bf16* vrow = Vt + (size_t)(batch * 64 + a) * S_DIM + s0 + sg;
#pragma unroll
        for (int h = 0; h < 2; ++h) {
            v8bf pk;
#pragma unroll
            for (int j = 0; j < 8; ++j) pk[j] = (__bf16)Tv[sg + h * 8 + j][a];
            *(v8bf*)(vrow + h * 8) = pk;
        }
    }
}

// ---------------------------------------------------------------------------
// Causal flash attention v4 (unchanged): split-K, no-max softmax,
// minimal live registers; acc_o MFMA-only -> AGPRs; Pt wave-private.
// ---------------------------------------------------------------------------
__global__ __launch_bounds__(256, 2) void attn_mfma(
    const __bf16* __restrict__ Qb,
    const __bf16* __restrict__ Kb,
    const __bf16* __restrict__ Vt,
    float* __restrict__ P_l,
    float* __restrict__ P_o,
    float* __restrict__ out)
{
    const int b = blockIdx.y;
    const int x = blockIdx.x;
    int qt, ks;
    if (x < 16)      { qt = x;                    ks = 0; }
    else if (x < 48) { qt = 16 + ((x - 16) >> 1); ks = (x - 16) & 1; }
    else if (x < 96) { int y = x - 48; qt = 32 + y / 3;  ks = y % 3; }
    else             { int y = x - 96; qt = 48 + (y >> 2); ks = y & 3; }
    const int nch = (qt >> 4) + 1;

    const int w    = threadIdx.x >> 6;
    const int lane = threadIdx.x & 63;
    const int L    = lane & 15;
    const int quad = lane >> 4;

    __shared__ __align__(16) char smem[67840];
    __bf16 (*Pt)[64][72]   = (__bf16(*)[64][72])smem;           // loop phase
    float*  red_l          = (float*)smem;                      // combine phase
    float (*red_o)[64][65] = (float(*)[64][65])(smem + 1024);
    float*  invs           = (float*)(smem + 67584);

    v8bf qf[4][2];
#pragma unroll
    for (int ni = 0; ni < 4; ++ni)
#pragma unroll
        for (int ka = 0; ka < 2; ++ka)
            qf[ni][ka] = *(const v8bf*)(Qb +
                (size_t)(b * S_DIM + qt * 64 + ni * 16 + L) * A_DIM + ka * 32 + quad * 8);

    v4f acc_o[4][4];
#pragma unroll
    for (int i = 0; i < 4; ++i)
#pragma unroll
        for (int j = 0; j < 4; ++j) acc_o[i][j] = (v4f){0.f, 0.f, 0.f, 0.f};
    float lrun[4] = {0.f, 0.f, 0.f, 0.f};

    const int kt0   = ks * 16 + w;
    const int ktmax = min(ks * 16 + 15, qt);

    for (int kt = kt0; kt <= ktmax; kt += 4) {
        v8bf kf[4][2];
#pragma unroll
        for (int mi = 0; mi < 4; ++mi)
#pragma unroll
            for (int ka = 0; ka < 2; ++ka)
                kf[mi][ka] = *(const v8bf*)(Kb +
                    (size_t)(b * S_DIM + kt * 64 + mi * 16 + L) * A_DIM + ka * 32 + quad * 8);
        v8bf vf[4][2];
#pragma unroll
        for (int ma = 0; ma < 4; ++ma)
#pragma unroll
            for (int ki = 0; ki < 2; ++ki)
                vf[ma][ki] = *(const v8bf*)(Vt +
                    (size_t)(b * 64 + ma * 16 + L) * S_DIM + kt * 64 + ki * 32 + quad * 8);

        const bool diag = (kt == qt);

#pragma unroll
        for (int ni = 0; ni < 4; ++ni) {
            v4f s[4];
#pragma unroll
            for (int mi = 0; mi < 4; ++mi) s[mi] = (v4f){0.f, 0.f, 0.f, 0.f};
#pragma unroll
            for (int mi = 0; mi < 4; ++mi)
#pragma unroll
                for (int ka = 0; ka < 2; ++ka)
                    s[mi] = mfma16(kf[mi][ka], qf[ni][ka], s[mi]);

            float rs = 0.f;
#pragma unroll
            for (int mi = 0; mi < 4; ++mi) {
                v4bf p4;
#pragma unroll
                for (int r = 0; r < 4; ++r) {
                    const bool masked = diag && (mi * 16 + quad * 4 + r > ni * 16 + L);
                    const float p = masked ? 0.f : __expf(s[mi][r]);
                    rs += p;
                    p4[r] = (__bf16)p;
                }
                *(v4bf*)&Pt[w][ni * 16 + L][mi * 16 + quad * 4] = p4;
            }
            lrun[ni] += rs;
        }

        v8bf pf[4][2];
#pragma unroll
        for (int ni = 0; ni < 4; ++ni)
#pragma unroll
            for (int ki = 0; ki < 2; ++ki)
                pf[ni][ki] = *(const v8bf*)&Pt[w][ni * 16 + L][ki * 32 + quad * 8];
#pragma unroll
        for (int ma = 0; ma < 4; ++ma)
#pragma unroll
            for (int ni = 0; ni < 4; ++ni)
#pragma unroll
                for (int ki = 0; ki < 2; ++ki)
                    acc_o[ma][ni] = mfma16(vf[ma][ki], pf[ni][ki], acc_o[ma][ni]);
    }

#pragma unroll
    for (int ni = 0; ni < 4; ++ni) {
        lrun[ni] += __shfl_xor(lrun[ni], 16, 64);
        lrun[ni] += __shfl_xor(lrun[ni], 32, 64);
    }

    __syncthreads();

    if (quad == 0) {
#pragma unroll
        for (int ni = 0; ni < 4; ++ni)
            red_l[w * 64 + ni * 16 + L] = lrun[ni];
    }
#pragma unroll
    for (int ma = 0; ma < 4; ++ma)
#pragma unroll
        for (int ni = 0; ni < 4; ++ni)
#pragma unroll
            for (int r = 0; r < 4; ++r)
                red_o[w][ma * 16 + quad * 4 + r][ni * 16 + L] = acc_o[ma][ni][r];
    __syncthreads();

    const int pidx = (b * 64 + qt) * 4 + ks;
    if (threadIdx.x < 64) {
        const int q = threadIdx.x;
        const float denom = red_l[0 * 64 + q] + red_l[1 * 64 + q]
                          + red_l[2 * 64 + q] + red_l[3 * 64 + q];
        if (nch == 1) {
            invs[q] = 1.0f / denom;
        } else {
            P_l[(size_t)pidx * 64 + q] = denom;
            invs[q] = 1.0f;
        }
    }
    __syncthreads();

    {
        const int q  = threadIdx.x >> 2;
        const int ac = (threadIdx.x & 3) << 4;
        const float sc = invs[q];
        float* dst = (nch == 1)
            ? out + (size_t)(b * S_DIM + qt * 64 + q) * A_DIM
            : P_o + (size_t)pidx * 4096 + (size_t)q * 64;
#pragma unroll
        for (int i4 = 0; i4 < 4; ++i4) {
            float vv[4];
#pragma unroll
            for (int j = 0; j < 4; ++j) {
                const int a = ac + i4 * 4 + j;
                vv[j] = sc * (red_o[0][a][q] + red_o[1][a][q]
                            + red_o[2][a][q] + red_o[3][a][q]);
            }
            *(float4*)(dst + ac + i4 * 4) = make_float4(vv[0], vv[1], vv[2], vv[3]);
        }
    }
}

// ---------------------------------------------------------------------------
// Combine split-K partials for qt >= 16: out = (sum_c O_c) / (sum_c l_c).
// ---------------------------------------------------------------------------
__global__ __launch_bounds__(256) void attn_combine(
    const float* __restrict__ P_l, const float* __restrict__ P_o,
    float* __restrict__ out)
{
    const int qt  = 16 + blockIdx.x;
    const int b   = blockIdx.y;
    const int nch = (qt >> 4) + 1;
    const int base = (b * 64 + qt) * 4;

    __shared__ float inv_s[64];
    if (threadIdx.x < 64) {
        const int q = threadIdx.x;
        float denom = 0.f;
        for (int c = 0; c < nch; ++c)
            denom += P_l[(size_t)(base + c) * 64 + q];
        inv_s[q] = 1.0f / denom;
    }
    __syncthreads();

    const int q  = threadIdx.x >> 2;
    const int ac = (threadIdx.x & 3) << 4;
    const float inv = inv_s[q];
    float* orow = out + (size_t)(b * S_DIM + qt * 64 + q) * A_DIM;
#pragma unroll
    for (int i4 = 0; i4 < 4; ++i4) {
        float4 acc = make_float4(0.f, 0.f, 0.f, 0.f);
        for (int c = 0; c < nch; ++c) {
            float4 v = *(const float4*)(P_o + (size_t)(base + c) * 4096 +
                                        (size_t)q * 64 + ac + i4 * 4);
            acc.x += v.x; acc.y += v.y; acc.z += v.z; acc.w += v.w;
        }
        acc.x *= inv; acc.y *= inv; acc.z *= inv; acc.w *= inv;
        *(float4*)(orow + ac + i4 * 4) = acc;
    }
}

// ---------------------------------------------------------------------------
extern "C" void kernel_launch(void* const* d_in, const int* in_sizes, int n_in,
                              void* d_out, int out_size, void* d_ws, size_t ws_size,
                              hipStream_t stream)
{
    const float* X  = (const float*)d_in[0];
    const float* Wk = (const float*)d_in[1];
    const float* Wq = (const float*)d_in[2];
    const float* Wv = (const float*)d_in[3];
    float* out = (float*)d_out;

    __bf16* Kb = (__bf16*)d_ws;                     // [16384][64]
    __bf16* Qb = Kb + (size_t)M_TOT * A_DIM;        // [16384][64] (x 1/8)
    __bf16* Vt = Qb + (size_t)M_TOT * A_DIM;        // [256][4096] V^T
    __bf16* Wb = Vt + (size_t)M_TOT * A_DIM;        // [192][1024]
    float*  P_l = (float*)(Wb + 3 * 65536);         // [1024][64]
    float*  P_o = P_l + 65536;                      // [1024][64][64]
    float*  Pp  = P_o + (size_t)1024 * 4096;        // [2][16384][192] fp32

    wconv_kernel<<<192, 256, 0, stream>>>(Wk, Wq, Wv, Wb);

    qkv_proj_mfma<<<2048, 256, 0, stream>>>(X, Wb, Pp);

    qkv_reduce<<<256, 256, 0, stream>>>(Pp, Kb, Qb, Vt);

    dim3 g2(160, B_DIM), b2(256);
    attn_mfma<<<g2, b2, 0, stream>>>(Qb, Kb, Vt, P_l, P_o, out);

    dim3 g3(48, B_DIM), b3(256);
    attn_combine<<<g3, b3, 0, stream>>>(P_l, P_o, out);
}

// Round 10
// 154.103 us; speedup vs baseline: 1.3710x; 1.3710x over previous
//
#include <hip/hip_runtime.h>
#include <math.h>

#define B_DIM 4
#define S_DIM 4096
#define E_DIM 1024
#define A_DIM 64
#define M_TOT (B_DIM * S_DIM) /* 16384 */

typedef __bf16 v8bf __attribute__((ext_vector_type(8)));
typedef __bf16 v4bf __attribute__((ext_vector_type(4)));
typedef float  v4f  __attribute__((ext_vector_type(4)));

__device__ __forceinline__ v4f mfma16(v8bf a, v8bf b, v4f c) {
    return __builtin_amdgcn_mfma_f32_16x16x32_bf16(a, b, c, 0, 0, 0);
}

// async global->LDS DMA, 16B per lane.  Dest = wave-uniform base + lane*16.
__device__ __forceinline__ void lds_dma16(const void* g, void* l) {
    __builtin_amdgcn_global_load_lds(
        (const __attribute__((address_space(1))) unsigned int*)g,
        (__attribute__((address_space(3))) unsigned int*)l, 16, 0, 0);
}

// ---------------------------------------------------------------------------
// Pre-pass: fp32 weights -> bf16 Wb[192][1024] (rows 0-63 K, 64-127 Q, 128-191 V).
// ---------------------------------------------------------------------------
__global__ __launch_bounds__(256) void wconv_kernel(
    const float* __restrict__ Wk, const float* __restrict__ Wq,
    const float* __restrict__ Wv, __bf16* __restrict__ Wb)
{
    const int i = blockIdx.x * 256 + threadIdx.x;   // float4 index, 49152 total
    const int w = i >> 14;
    const int off = (i & 16383) * 4;
    const float* s = ((w == 0) ? Wk : (w == 1) ? Wq : Wv) + off;
    float4 v = *(const float4*)s;
    v4bf o;
    o[0] = (__bf16)v.x; o[1] = (__bf16)v.y; o[2] = (__bf16)v.z; o[3] = (__bf16)v.w;
    *(v4bf*)(Wb + (size_t)w * 65536 + off) = o;
}

// ---------------------------------------------------------------------------
// Fused QKV projection v8: canonical LDS-staged MFMA GEMM (m97 pattern).
// 256 blocks x 4 waves; block = 64 rows x 192 cols; K = 16 chunks of 64.
// B (bf16): global_load_lds DMA, XOR k-chunk swizzle -> conflict-free b128
// fragment reads without padding.  X (fp32): coalesced float4 loads -> cvt
// bf16 -> padded LDS (double-buffered; loads fly under compute).
// All fragment reads are ds_read_b128 -> the 16-segment global gather that
// capped v4-v7 at 65-87 us is gone.  Epilogue: K, Q (x1/8), V^T direct.
// ---------------------------------------------------------------------------
__global__ __launch_bounds__(256) void qkv_proj_mfma(
    const float* __restrict__ X,
    const __bf16* __restrict__ Wb,   // [192][1024]
    __bf16* __restrict__ Kb,
    __bf16* __restrict__ Qb,
    __bf16* __restrict__ Vt)
{
    const int r0   = blockIdx.x * 64;
    const int w    = threadIdx.x >> 6;
    const int lane = threadIdx.x & 63;
    const int L    = lane & 15;
    const int quad = lane >> 4;
    const int cbase = w * 48;

    // Xs[2][64][72] bf16 (padded rows) | Bs[2][192][64] bf16 (DMA, swizzled)
    __shared__ __align__(16) char smem[18432 + 49152];
    __bf16* Xs = (__bf16*)smem;                  // 2 x 4608 elems
    __bf16* Bs = (__bf16*)(smem + 18432);        // 2 x 12288 elems
    float (*Tv)[65] = (float(*)[65])smem;        // epilogue union

    v4f acc[4][3]; // [mi][nt]
#pragma unroll
    for (int mi = 0; mi < 4; ++mi)
#pragma unroll
        for (int nt = 0; nt < 3; ++nt) acc[mi][nt] = (v4f){0.f, 0.f, 0.f, 0.f};

    // ---- B staging: 6 DMA issues/wave, rows [w*48, w*48+48), XOR swizzle ----
    const int brow_l  = lane >> 3;          // 0..7 within an 8-row issue
    const int bchunk  = lane & 7;           // 16B k-chunk slot
    const int bgchunk = bchunk ^ brow_l;    // fetched k-chunk (slot^row parity)
    auto stageB = [&](int kc, int buf) {
#pragma unroll
        for (int j = 0; j < 6; ++j) {
            const int rowbase = w * 48 + j * 8;
            const __bf16* g = Wb + (size_t)(rowbase + brow_l) * E_DIM
                              + kc * 64 + bgchunk * 8;
            lds_dma16(g, Bs + buf * 12288 + rowbase * 64);
        }
    };

    // ---- X staging: 4 float4/thread, coalesced (4 rows x 256B per issue) ----
    const int xrow_i = (lane >> 4);         // row within 4-row issue group
    const int xcol   = (lane & 15) * 4;     // float offset
    float4 xr[4];
    auto loadX = [&](int kc) {
#pragma unroll
        for (int i = 0; i < 4; ++i) {
            const int row = i * 16 + w * 4 + xrow_i;
            xr[i] = *(const float4*)(X + (size_t)(r0 + row) * E_DIM + kc * 64 + xcol);
        }
    };
    auto flushX = [&](int buf) {
#pragma unroll
        for (int i = 0; i < 4; ++i) {
            const int row = i * 16 + w * 4 + xrow_i;
            v4bf o;
            o[0] = (__bf16)xr[i].x; o[1] = (__bf16)xr[i].y;
            o[2] = (__bf16)xr[i].z; o[3] = (__bf16)xr[i].w;
            *(v4bf*)(Xs + buf * 4608 + row * 72 + xcol) = o;
        }
    };

    // prologue
    stageB(0, 0);
    loadX(0);
    flushX(0);
    __syncthreads(); // DMA drained + Xs[0] visible

#pragma unroll 1
    for (int kc = 0; kc < 16; ++kc) {
        const int cur = kc & 1;
        if (kc < 15) {
            stageB(kc + 1, cur ^ 1);
            loadX(kc + 1);
        }
        // ---- compute chunk kc from LDS ----
        v8bf afr[4][2];
#pragma unroll
        for (int mi = 0; mi < 4; ++mi)
#pragma unroll
            for (int ka = 0; ka < 2; ++ka)
                afr[mi][ka] = *(const v8bf*)(Xs + cur * 4608 +
                                (mi * 16 + L) * 72 + ka * 32 + quad * 8);
        v8bf bfr[3][2];
#pragma unroll
        for (int nt = 0; nt < 3; ++nt)
#pragma unroll
            for (int ka = 0; ka < 2; ++ka) {
                const int R = cbase + nt * 16 + L;
                const int slot = (ka * 4 + quad) ^ (R & 7);
                bfr[nt][ka] = *(const v8bf*)(Bs + cur * 12288 + R * 64 + slot * 8);
            }
#pragma unroll
        for (int mi = 0; mi < 4; ++mi)
#pragma unroll
            for (int nt = 0; nt < 3; ++nt)
#pragma unroll
                for (int ka = 0; ka < 2; ++ka)
                    acc[mi][nt] = mfma16(afr[mi][ka], bfr[nt][ka], acc[mi][nt]);

        if (kc < 15) flushX(cur ^ 1);
        __syncthreads(); // next DMA drained, Xs flushed, cur reads done
    }

    // ---- epilogue: K (cols<64), Q (<128, x1/8), V (->LDS transpose) ----
#pragma unroll
    for (int nt = 0; nt < 3; ++nt) {
        const int c0 = cbase + nt * 16; // wave-uniform; tiles never straddle
        if (c0 < 64) {
#pragma unroll
            for (int mi = 0; mi < 4; ++mi)
#pragma unroll
                for (int r = 0; r < 4; ++r)
                    Kb[(size_t)(r0 + mi * 16 + quad * 4 + r) * A_DIM + c0 + L] =
                        (__bf16)acc[mi][nt][r];
        } else if (c0 < 128) {
#pragma unroll
            for (int mi = 0; mi < 4; ++mi)
#pragma unroll
                for (int r = 0; r < 4; ++r)
                    Qb[(size_t)(r0 + mi * 16 + quad * 4 + r) * A_DIM + (c0 - 64) + L] =
                        (__bf16)(acc[mi][nt][r] * 0.125f);
        } else {
#pragma unroll
            for (int mi = 0; mi < 4; ++mi)
#pragma unroll
                for (int r = 0; r < 4; ++r)
                    Tv[mi * 16 + quad * 4 + r][(c0 - 128) + L] = acc[mi][nt][r];
        }
    }
    __syncthreads();

    // transposed V write: thread t -> V-col a = t>>2, s-quarter = t&3
    {
        const int batch = r0 >> 12;
        const int s0    = r0 & 4095;
        const int a     = threadIdx.x >> 2;
        const int part  = threadIdx.x & 3;
        __bf16* vrow = Vt + (size_t)(batch * 64 + a) * S_DIM + s0 + part * 16;
#pragma unroll
        for (int h = 0; h < 2; ++h) {
            v8bf pk;
#pragma unroll
            for (int j = 0; j < 8; ++j)
                pk[j] = (__bf16)Tv[part * 16 + h * 8 + j][a];
            *(v8bf*)(vrow + h * 8) = pk;
        }
    }
}

// ---------------------------------------------------------------------------
// Causal flash attention v4 (unchanged): split-K, no-max softmax,
// minimal live registers; acc_o MFMA-only -> AGPRs; Pt wave-private.
// ---------------------------------------------------------------------------
__global__ __launch_bounds__(256, 2) void attn_mfma(
    const __bf16* __restrict__ Qb,
    const __bf16* __restrict__ Kb,
    const __bf16* __restrict__ Vt,
    float* __restrict__ P_l,
    float* __restrict__ P_o,
    float* __restrict__ out)
{
    const int b = blockIdx.y;
    const int x = blockIdx.x;
    int qt, ks;
    if (x < 16)      { qt = x;                    ks = 0; }
    else if (x < 48) { qt = 16 + ((x - 16) >> 1); ks = (x - 16) & 1; }
    else if (x < 96) { int y = x - 48; qt = 32 + y / 3;  ks = y % 3; }
    else             { int y = x - 96; qt = 48 + (y >> 2); ks = y & 3; }
    const int nch = (qt >> 4) + 1;

    const int w    = threadIdx.x >> 6;
    const int lane = threadIdx.x & 63;
    const int L    = lane & 15;
    const int quad = lane >> 4;

    __shared__ __align__(16) char smem[67840];
    __bf16 (*Pt)[64][72]   = (__bf16(*)[64][72])smem;           // loop phase
    float*  red_l          = (float*)smem;                      // combine phase
    float (*red_o)[64][65] = (float(*)[64][65])(smem + 1024);
    float*  invs           = (float*)(smem + 67584);

    v8bf qf[4][2];
#pragma unroll
    for (int ni = 0; ni < 4; ++ni)
#pragma unroll
        for (int ka = 0; ka < 2; ++ka)
            qf[ni][ka] = *(const v8bf*)(Qb +
                (size_t)(b * S_DIM + qt * 64 + ni * 16 + L) * A_DIM + ka * 32 + quad * 8);

    v4f acc_o[4][4];
#pragma unroll
    for (int i = 0; i < 4; ++i)
#pragma unroll
        for (int j = 0; j < 4; ++j) acc_o[i][j] = (v4f){0.f, 0.f, 0.f, 0.f};
    float lrun[4] = {0.f, 0.f, 0.f, 0.f};

    const int kt0   = ks * 16 + w;
    const int ktmax = min(ks * 16 + 15, qt);

    for (int kt = kt0; kt <= ktmax; kt += 4) {
        v8bf kf[4][2];
#pragma unroll
        for (int mi = 0; mi < 4; ++mi)
#pragma unroll
            for (int ka = 0; ka < 2; ++ka)
                kf[mi][ka] = *(const v8bf*)(Kb +
                    (size_t)(b * S_DIM + kt * 64 + mi * 16 + L) * A_DIM + ka * 32 + quad * 8);
        v8bf vf[4][2];
#pragma unroll
        for (int ma = 0; ma < 4; ++ma)
#pragma unroll
            for (int ki = 0; ki < 2; ++ki)
                vf[ma][ki] = *(const v8bf*)(Vt +
                    (size_t)(b * 64 + ma * 16 + L) * S_DIM + kt * 64 + ki * 32 + quad * 8);

        const bool diag = (kt == qt);

#pragma unroll
        for (int ni = 0; ni < 4; ++ni) {
            v4f s[4];
#pragma unroll
            for (int mi = 0; mi < 4; ++mi) s[mi] = (v4f){0.f, 0.f, 0.f, 0.f};
#pragma unroll
            for (int mi = 0; mi < 4; ++mi)
#pragma unroll
                for (int ka = 0; ka < 2; ++ka)
                    s[mi] = mfma16(kf[mi][ka], qf[ni][ka], s[mi]);

            float rs = 0.f;
#pragma unroll
            for (int mi = 0; mi < 4; ++mi) {
                v4bf p4;
#pragma unroll
                for (int r = 0; r < 4; ++r) {
                    const bool masked = diag && (mi * 16 + quad * 4 + r > ni * 16 + L);
                    const float p = masked ? 0.f : __expf(s[mi][r]);
                    rs += p;
                    p4[r] = (__bf16)p;
                }
                *(v4bf*)&Pt[w][ni * 16 + L][mi * 16 + quad * 4] = p4;
            }
            lrun[ni] += rs;
        }

        v8bf pf[4][2];
#pragma unroll
        for (int ni = 0; ni < 4; ++ni)
#pragma unroll
            for (int ki = 0; ki < 2; ++ki)
                pf[ni][ki] = *(const v8bf*)&Pt[w][ni * 16 + L][ki * 32 + quad * 8];
#pragma unroll
        for (int ma = 0; ma < 4; ++ma)
#pragma unroll
            for (int ni = 0; ni < 4; ++ni)
#pragma unroll
                for (int ki = 0; ki < 2; ++ki)
                    acc_o[ma][ni] = mfma16(vf[ma][ki], pf[ni][ki], acc_o[ma][ni]);
    }

#pragma unroll
    for (int ni = 0; ni < 4; ++ni) {
        lrun[ni] += __shfl_xor(lrun[ni], 16, 64);
        lrun[ni] += __shfl_xor(lrun[ni], 32, 64);
    }

    __syncthreads();

    if (quad == 0) {
#pragma unroll
        for (int ni = 0; ni < 4; ++ni)
            red_l[w * 64 + ni * 16 + L] = lrun[ni];
    }
#pragma unroll
    for (int ma = 0; ma < 4; ++ma)
#pragma unroll
        for (int ni = 0; ni < 4; ++ni)
#pragma unroll
            for (int r = 0; r < 4; ++r)
                red_o[w][ma * 16 + quad * 4 + r][ni * 16 + L] = acc_o[ma][ni][r];
    __syncthreads();

    const int pidx = (b * 64 + qt) * 4 + ks;
    if (threadIdx.x < 64) {
        const int q = threadIdx.x;
        const float denom = red_l[0 * 64 + q] + red_l[1 * 64 + q]
                          + red_l[2 * 64 + q] + red_l[3 * 64 + q];
        if (nch == 1) {
            invs[q] = 1.0f / denom;
        } else {
            P_l[(size_t)pidx * 64 + q] = denom;
            invs[q] = 1.0f;
        }
    }
    __syncthreads();

    {
        const int q  = threadIdx.x >> 2;
        const int ac = (threadIdx.x & 3) << 4;
        const float sc = invs[q];
        float* dst = (nch == 1)
            ? out + (size_t)(b * S_DIM + qt * 64 + q) * A_DIM
            : P_o + (size_t)pidx * 4096 + (size_t)q * 64;
#pragma unroll
        for (int i4 = 0; i4 < 4; ++i4) {
            float vv[4];
#pragma unroll
            for (int j = 0; j < 4; ++j) {
                const int a = ac + i4 * 4 + j;
                vv[j] = sc * (red_o[0][a][q] + red_o[1][a][q]
                            + red_o[2][a][q] + red_o[3][a][q]);
            }
            *(float4*)(dst + ac + i4 * 4) = make_float4(vv[0], vv[1], vv[2], vv[3]);
        }
    }
}

// ---------------------------------------------------------------------------
// Combine split-K partials for qt >= 16: out = (sum_c O_c) / (sum_c l_c).
// ---------------------------------------------------------------------------
__global__ __launch_bounds__(256) void attn_combine(
    const float* __restrict__ P_l, const float* __restrict__ P_o,
    float* __restrict__ out)
{
    const int qt  = 16 + blockIdx.x;
    const int b   = blockIdx.y;
    const int nch = (qt >> 4) + 1;
    const int base = (b * 64 + qt) * 4;

    __shared__ float inv_s[64];
    if (threadIdx.x < 64) {
        const int q = threadIdx.x;
        float denom = 0.f;
        for (int c = 0; c < nch; ++c)
            denom += P_l[(size_t)(base + c) * 64 + q];
        inv_s[q] = 1.0f / denom;
    }
    __syncthreads();

    const int q  = threadIdx.x >> 2;
    const int ac = (threadIdx.x & 3) << 4;
    const float inv = inv_s[q];
    float* orow = out + (size_t)(b * S_DIM + qt * 64 + q) * A_DIM;
#pragma unroll
    for (int i4 = 0; i4 < 4; ++i4) {
        float4 acc = make_float4(0.f, 0.f, 0.f, 0.f);
        for (int c = 0; c < nch; ++c) {
            float4 v = *(const float4*)(P_o + (size_t)(base + c) * 4096 +
                                        (size_t)q * 64 + ac + i4 * 4);
            acc.x += v.x; acc.y += v.y; acc.z += v.z; acc.w += v.w;
        }
        acc.x *= inv; acc.y *= inv; acc.z *= inv; acc.w *= inv;
        *(float4*)(orow + ac + i4 * 4) = acc;
    }
}

// ---------------------------------------------------------------------------
extern "C" void kernel_launch(void* const* d_in, const int* in_sizes, int n_in,
                              void* d_out, int out_size, void* d_ws, size_t ws_size,
                              hipStream_t stream)
{
    const float* X  = (const float*)d_in[0];
    const float* Wk = (const float*)d_in[1];
    const float* Wq = (const float*)d_in[2];
    const float* Wv = (const float*)d_in[3];
    float* out = (float*)d_out;

    __bf16* Kb = (__bf16*)d_ws;                     // [16384][64]
    __bf16* Qb = Kb + (size_t)M_TOT * A_DIM;        // [16384][64] (x 1/8)
    __bf16* Vt = Qb + (size_t)M_TOT * A_DIM;        // [256][4096] V^T
    __bf16* Wb = Vt + (size_t)M_TOT * A_DIM;        // [192][1024]
    float*  P_l = (float*)(Wb + 3 * 65536);         // [1024][64]
    float*  P_o = P_l + 65536;                      // [1024][64][64]

    wconv_kernel<<<192, 256, 0, stream>>>(Wk, Wq, Wv, Wb);

    qkv_proj_mfma<<<256, 256, 0, stream>>>(X, Wb, Kb, Qb, Vt);

    dim3 g2(160, B_DIM), b2(256);
    attn_mfma<<<g2, b2, 0, stream>>>(Qb, Kb, Vt, P_l, P_o, out);

    dim3 g3(48, B_DIM), b3(256);
    attn_combine<<<g3, b3, 0, stream>>>(P_l, P_o, out);
}